// Round 15
// baseline (324.837 us; speedup 1.0000x reference)
//
#include <hip/hip_runtime.h>
#include <cmath>

static constexpr int TPB = 256;

using short8 = __attribute__((ext_vector_type(8))) short;
using half8  = __attribute__((ext_vector_type(8))) _Float16;
using f32x4  = __attribute__((ext_vector_type(4))) float;
using uint4v = __attribute__((ext_vector_type(4))) unsigned int;
typedef unsigned short ushort;
typedef unsigned int uint;

// fp16 helpers (RNE via hardware convert)
__device__ __forceinline__ ushort f2h(float f) {
  _Float16 h = (_Float16)f;
  return __builtin_bit_cast(ushort, h);
}
__device__ __forceinline__ float h2f(ushort u) {
  return (float)__builtin_bit_cast(_Float16, u);
}
__device__ __forceinline__ float hlo(uint u) { return h2f((ushort)(u & 0xffffu)); }
__device__ __forceinline__ float hhi(uint u) { return h2f((ushort)(u >> 16)); }

// ---------- all three W [K][Nc] fp32 -> Wt [Nc][K] fp16, one launch ----------
__global__ void prep_wt3(const float* __restrict__ W1, ushort* __restrict__ Wt1,
                         const float* __restrict__ W2, ushort* __restrict__ Wt2,
                         const float* __restrict__ W3, ushort* __restrict__ Wt3,
                         int FIN) {
  int idx = blockIdx.x * TPB + threadIdx.x;
  const int n1 = FIN * 128, n2 = 128 * 128, n3 = 128 * 64;
  if (idx < n1) {
    int nc = idx / FIN, k = idx - nc * FIN;
    Wt1[idx] = f2h(W1[(size_t)k * 128 + nc]);
  } else if (idx < n1 + n2) {
    int i = idx - n1;
    int nc = i / 128, k = i - nc * 128;
    Wt2[i] = f2h(W2[(size_t)k * 128 + nc]);
  } else if (idx < n1 + n2 + n3) {
    int i = idx - n1 - n2;
    int nc = i / 128, k = i - nc * 128;
    Wt3[i] = f2h(W3[(size_t)k * 64 + nc]);
  }
}

// ---------- MFMA GEMM (fp16), double-buffered LDS, 1 barrier/K-step ----------
// BM=64, BN=Nc (64 or 128), BK=64, 256 threads = 4 waves (2 row x 2 col)
// FUSEMODE: 0 = none; 1 = 4-head als/ald (BN=128, C=32); 2 = 1-head als/ald (BN=64)
template <int ABF16, int BN, int FUSEMODE>
__global__ __launch_bounds__(256) void gemm_mfma(const void* __restrict__ Ap,
                                                 const ushort* __restrict__ Wt,
                                                 ushort* __restrict__ Cb,
                                                 int n, int K,
                                                 const float* __restrict__ a_s,
                                                 const float* __restrict__ a_d,
                                                 float* __restrict__ als,
                                                 float* __restrict__ ald) {
  constexpr int NF = BN / 32;  // col frags per wave (4 or 2)
  __shared__ short As[2][64 * 72];
  __shared__ short Bs[2][BN * 72];
  const int tid = threadIdx.x;
  const int row0 = blockIdx.x * 64;
  const int srow = tid >> 2, sks = (tid & 3) << 4;  // A staging
  const int brow = tid >> 1, bks = (tid & 1) << 5;  // B staging (BN=128)
  const int wave = tid >> 6, lane = tid & 63;
  const int wr = wave >> 1, wc = wave & 1;
  const int lm = lane & 15, lg = lane >> 4;

  f32x4 acc[2][NF] = {};

  // staging registers: raw loads only (converts deferred to WRITET so no
  // waitcnt lands before the MFMA block — the whole point of the pipeline)
  float4 fa0, fa1, fa2, fa3;       // layer-1 fp32 A
  short8 sa0, sa1;                 // fp16 A
  short8 sb0, sb1, sb2, sb3;       // B
  bool arow_ok;

  auto LOADT = [&](int k0) {
    int gr = row0 + srow;
    arow_ok = gr < n;
    if constexpr (ABF16 == 0) {
      const float* A = (const float*)Ap;
      if (arow_ok) {
        const float* p = A + (size_t)gr * K + k0 + sks;
        fa0 = *(const float4*)(p + 0);
        fa1 = *(const float4*)(p + 4);
        fa2 = *(const float4*)(p + 8);
        fa3 = *(const float4*)(p + 12);
      }
    } else {
      const ushort* A = (const ushort*)Ap;
      if (arow_ok) {
        const ushort* p = A + (size_t)gr * K + k0 + sks;
        sa0 = *(const short8*)(p + 0);
        sa1 = *(const short8*)(p + 8);
      }
    }
    if constexpr (BN == 128) {
      const ushort* wp = Wt + (size_t)brow * K + k0 + bks;
      sb0 = *(const short8*)(wp + 0);
      sb1 = *(const short8*)(wp + 8);
      sb2 = *(const short8*)(wp + 16);
      sb3 = *(const short8*)(wp + 24);
    } else {
      const ushort* wp = Wt + (size_t)srow * K + k0 + sks;
      sb0 = *(const short8*)(wp + 0);
      sb1 = *(const short8*)(wp + 8);
    }
  };
  auto WRITET = [&](int b) {
    short8 w0, w1;
    if constexpr (ABF16 == 0) {
      short8 z = {0, 0, 0, 0, 0, 0, 0, 0};
      w0 = z; w1 = z;
      if (arow_ok) {
        w0[0] = (short)f2h(fa0.x); w0[1] = (short)f2h(fa0.y); w0[2] = (short)f2h(fa0.z); w0[3] = (short)f2h(fa0.w);
        w0[4] = (short)f2h(fa1.x); w0[5] = (short)f2h(fa1.y); w0[6] = (short)f2h(fa1.z); w0[7] = (short)f2h(fa1.w);
        w1[0] = (short)f2h(fa2.x); w1[1] = (short)f2h(fa2.y); w1[2] = (short)f2h(fa2.z); w1[3] = (short)f2h(fa2.w);
        w1[4] = (short)f2h(fa3.x); w1[5] = (short)f2h(fa3.y); w1[6] = (short)f2h(fa3.z); w1[7] = (short)f2h(fa3.w);
      }
    } else {
      short8 z = {0, 0, 0, 0, 0, 0, 0, 0};
      w0 = arow_ok ? sa0 : z;
      w1 = arow_ok ? sa1 : z;
    }
    *(short8*)&As[b][srow * 72 + sks + 0] = w0;
    *(short8*)&As[b][srow * 72 + sks + 8] = w1;
    if constexpr (BN == 128) {
      *(short8*)&Bs[b][brow * 72 + bks + 0]  = sb0;
      *(short8*)&Bs[b][brow * 72 + bks + 8]  = sb1;
      *(short8*)&Bs[b][brow * 72 + bks + 16] = sb2;
      *(short8*)&Bs[b][brow * 72 + bks + 24] = sb3;
    } else {
      *(short8*)&Bs[b][srow * 72 + sks + 0] = sb0;
      *(short8*)&Bs[b][srow * 72 + sks + 8] = sb1;
    }
  };

  LOADT(0);
  WRITET(0);
  __syncthreads();
  const int nk = K >> 6;
  for (int t = 0; t < nk; ++t) {
    const int cur = t & 1;
    const bool more = (t + 1) < nk;
    if (more) LOADT((t + 1) << 6);  // issue next-tile loads; consumed only in WRITET
#pragma unroll
    for (int kk = 0; kk < 64; kk += 32) {
      half8 a0 = *(const half8*)&As[cur][(wr * 32 + lm) * 72 + kk + lg * 8];
      half8 a1 = *(const half8*)&As[cur][(wr * 32 + 16 + lm) * 72 + kk + lg * 8];
      half8 bf[NF];
#pragma unroll
      for (int f = 0; f < NF; ++f)
        bf[f] = *(const half8*)&Bs[cur][(wc * (BN / 2) + f * 16 + lm) * 72 + kk + lg * 8];
#pragma unroll
      for (int f = 0; f < NF; ++f) {
        acc[0][f] = __builtin_amdgcn_mfma_f32_16x16x32_f16(a0, bf[f], acc[0][f], 0, 0, 0);
        acc[1][f] = __builtin_amdgcn_mfma_f32_16x16x32_f16(a1, bf[f], acc[1][f], 0, 0, 0);
      }
    }
    if (more) {
      WRITET(cur ^ 1);   // other buffer: iteration-(t-1) readers already barriered
      __syncthreads();
    }
  }
#pragma unroll
  for (int m = 0; m < 2; ++m)
#pragma unroll
    for (int f = 0; f < NF; ++f)
#pragma unroll
      for (int r = 0; r < 4; ++r) {
        int row = row0 + wr * 32 + m * 16 + lg * 4 + r;
        if (row < n) {
          int col = wc * (BN / 2) + f * 16 + lm;
          Cb[(size_t)row * BN + col] = f2h(acc[m][f][r]);
        }
      }
  if constexpr (FUSEMODE == 1) {
    // 4-head logits: head = 2*wc + hh, 32 contiguous cols fully in-wave
#pragma unroll
    for (int hh = 0; hh < 2; ++hh) {
      const int head = 2 * wc + hh;
      float as0 = a_s[head * 32 + lm], as1 = a_s[head * 32 + 16 + lm];
      float ad0 = a_d[head * 32 + lm], ad1 = a_d[head * 32 + 16 + lm];
#pragma unroll
      for (int m = 0; m < 2; ++m)
#pragma unroll
        for (int r = 0; r < 4; ++r) {
          float tS = acc[m][2 * hh][r] * as0 + acc[m][2 * hh + 1][r] * as1;
          float tD = acc[m][2 * hh][r] * ad0 + acc[m][2 * hh + 1][r] * ad1;
#pragma unroll
          for (int off = 8; off >= 1; off >>= 1) {
            tS += __shfl_xor(tS, off);
            tD += __shfl_xor(tD, off);
          }
          if (lm == 0) {
            int row = row0 + wr * 32 + m * 16 + lg * 4 + r;
            if (row < n) {
              als[(size_t)row * 4 + head] = tS;
              ald[(size_t)row * 4 + head] = tD;
            }
          }
        }
    }
  }
  if constexpr (FUSEMODE == 2) {
    // 1-head logits over 64 cols split across wc=0 (0-31) and wc=1 (32-63).
    __syncthreads();  // ensure all MFMA LDS reads done before reusing As as scratch
    float* alsp = (float*)&As[0][0];  // 64 floats
    float* aldp = alsp + 64;
    float tS[2][4], tD[2][4];
#pragma unroll
    for (int m = 0; m < 2; ++m)
#pragma unroll
      for (int r = 0; r < 4; ++r) {
        int col0c = wc * 32;
        float s = acc[m][0][r] * a_s[col0c + lm] + acc[m][1][r] * a_s[col0c + 16 + lm];
        float dd = acc[m][0][r] * a_d[col0c + lm] + acc[m][1][r] * a_d[col0c + 16 + lm];
#pragma unroll
        for (int off = 8; off >= 1; off >>= 1) {
          s += __shfl_xor(s, off);
          dd += __shfl_xor(dd, off);
        }
        tS[m][r] = s;
        tD[m][r] = dd;
      }
    if (wc == 0) {
#pragma unroll
      for (int m = 0; m < 2; ++m)
#pragma unroll
        for (int r = 0; r < 4; ++r)
          if (lm == 0) {
            int rl = wr * 32 + m * 16 + lg * 4 + r;
            alsp[rl] = tS[m][r];
            aldp[rl] = tD[m][r];
          }
    }
    __syncthreads();
    if (wc == 1) {
#pragma unroll
      for (int m = 0; m < 2; ++m)
#pragma unroll
        for (int r = 0; r < 4; ++r)
          if (lm == 0) {
            int rl = wr * 32 + m * 16 + lg * 4 + r;
            int row = row0 + rl;
            if (row < n) {
              als[row] = alsp[rl] + tS[m][r];
              ald[row] = aldp[rl] + tD[m][r];
            }
          }
    }
  }
}

// ---------- CSR build ----------
__global__ void zero_int(int* __restrict__ p, int n) {
  int i = blockIdx.x * TPB + threadIdx.x;
  if (i < n) p[i] = 0;
}

__global__ void hist_dst(const int* __restrict__ edst, int* __restrict__ counts,
                         int E0, int Et) {
  int e = blockIdx.x * TPB + threadIdx.x;
  if (e >= Et) return;
  int d = e < E0 ? edst[e] : e - E0;
  atomicAdd(&counts[d], 1);
}

__global__ void block_sums(const int* __restrict__ counts, int* __restrict__ bsum, int N) {
  __shared__ int sh[256];
  int t = threadIdx.x, idx = blockIdx.x * 256 + t;
  sh[t] = idx < N ? counts[idx] : 0;
  __syncthreads();
  for (int off = 128; off >= 1; off >>= 1) {
    if (t < off) sh[t] += sh[t + off];
    __syncthreads();
  }
  if (t == 0) bsum[blockIdx.x] = sh[0];
}

__global__ void scan_bsum(int* __restrict__ bsum, int nb) {
  __shared__ int sh[256];
  int t = threadIdx.x;
  int v = t < nb ? bsum[t] : 0;
  sh[t] = v;
  __syncthreads();
  for (int off = 1; off < 256; off <<= 1) {
    int u = (t >= off) ? sh[t - off] : 0;
    __syncthreads();
    sh[t] += u;
    __syncthreads();
  }
  if (t < nb) bsum[t] = sh[t] - v;  // exclusive
}

__global__ void scan_final(const int* __restrict__ counts, const int* __restrict__ bsum_ex,
                           int* __restrict__ offsets, int* __restrict__ cursor,
                           int N, int Et) {
  __shared__ int sh[256];
  int t = threadIdx.x, b = blockIdx.x;
  int idx = b * 256 + t;
  int v = (idx < N) ? counts[idx] : 0;
  sh[t] = v;
  __syncthreads();
  for (int off = 1; off < 256; off <<= 1) {
    int u = (t >= off) ? sh[t - off] : 0;
    __syncthreads();
    sh[t] += u;
    __syncthreads();
  }
  if (idx < N) {
    int o = bsum_ex[b] + sh[t] - v;
    offsets[idx] = o;
    cursor[idx] = o;
  }
  if (idx == 0) offsets[N] = Et;
}

__global__ void scatter_csr(const int* __restrict__ esrc, const int* __restrict__ edst,
                            int* __restrict__ cursor, int* __restrict__ csr_src,
                            int E0, int Et) {
  int e = blockIdx.x * TPB + threadIdx.x;
  if (e >= Et) return;
  int s = e < E0 ? esrc[e] : e - E0;
  int d = e < E0 ? edst[e] : e - E0;
  int pos = atomicAdd(&cursor[d], 1);
  csr_src[pos] = s;
}

// ---------- fused attention + bias + LayerNorm + ELU, one wave per dst node ----------
template <int HH, int CC>
__global__ __launch_bounds__(256) void fused_attn(
    const ushort* __restrict__ hb, const float* __restrict__ als,
    const float* __restrict__ ald, const int* __restrict__ offsets,
    const int* __restrict__ csr_src, const float* __restrict__ bias,
    const float* __restrict__ g, const float* __restrict__ be,
    ushort* __restrict__ xout, int n) {
  constexpr int W = HH * CC;        // 128 or 64
  constexpr int LPE = W / 8;        // 16 or 8 lanes per edge
  constexpr int NEG = 64 / LPE;     // 4 or 8 concurrent edges
  int wid = (int)((blockIdx.x * (size_t)blockDim.x + threadIdx.x) >> 6);
  int lane = threadIdx.x & 63;
  if (wid >= n) return;
  const int d = wid;
  const int begin = offsets[d], end = offsets[d + 1];
  const int deg = end - begin;

  const int grp = lane / LPE, sub = lane % LPE;
  const int c0 = sub * 8;

  float acc[8] = {};

  if (HH == 4 && deg <= 16) {
    // ======== FAST16 path: lane = (head h16, edge j16) ========
    const int h16 = lane >> 4, j16 = lane & 15;
    bool act = j16 < deg;
    int s_e = csr_src[begin + (act ? j16 : 0)];
    float e;
    {
      float ad_h = ald[(size_t)d * 4 + h16];
      e = act ? (als[(size_t)s_e * 4 + h16] + ad_h) : -1e30f;
      e = e > 0.f ? e : 0.2f * e;
    }
    float m = e;
#pragma unroll
    for (int off = 8; off >= 1; off >>= 1) m = fmaxf(m, __shfl_xor(m, off));
    float p = act ? __expf(e - m) : 0.f;
    float s = p;
#pragma unroll
    for (int off = 8; off >= 1; off >>= 1) s += __shfl_xor(s, off);
    float alpha = p / (s + 1e-16f);  // 0 for inactive lanes

    const int hc = sub >> 2;          // head of my channel block
    int j = grp;
    int sj = __shfl(s_e, j & 15);
    uint4v u = *(const uint4v*)(hb + (size_t)sj * W + c0);
    for (int j0 = 0; j0 < deg; j0 += NEG) {
      uint4v ucur = u;
      int jcur = j;
      j += NEG;
      if (j0 + NEG < deg) {
        int sn = __shfl(s_e, j & 15);
        u = *(const uint4v*)(hb + (size_t)sn * W + c0);
      }
      float w = __shfl(alpha, (hc << 4) | (jcur & 15));  // 0 if jcur >= deg
#pragma unroll
      for (int i = 0; i < 4; ++i) {
        acc[2 * i]     = fmaf(w, hlo(ucur[i]), acc[2 * i]);
        acc[2 * i + 1] = fmaf(w, hhi(ucur[i]), acc[2 * i + 1]);
      }
    }
  } else {

  const int hsel = sub >> 2;        // my head (HH=4)
  float aldv[HH];
  if constexpr (HH == 4) {
    float4 t = *(const float4*)(ald + (size_t)d * 4);
    aldv[0] = t.x; aldv[1] = t.y; aldv[2] = t.z; aldv[3] = t.w;
  } else {
    aldv[0] = ald[d];
  }

  auto sel4 = [&](float x0, float x1, float x2, float x3) {
    float lo = (hsel & 1) ? x1 : x0;
    float hi = (hsel & 1) ? x3 : x2;
    return (hsel & 2) ? hi : lo;
  };

  if (deg <= 64) {
    // ---- logits: one lane per edge ----
    bool act = lane < deg;
    int s_e = act ? csr_src[begin + lane] : 0;
    float e0 = -1e30f, e1 = -1e30f, e2 = -1e30f, e3 = -1e30f;
    if constexpr (HH == 4) {
      if (act) {
        float4 t = *(const float4*)(als + (size_t)s_e * 4);
        e0 = t.x + aldv[0]; e0 = e0 > 0.f ? e0 : 0.2f * e0;
        e1 = t.y + aldv[1]; e1 = e1 > 0.f ? e1 : 0.2f * e1;
        e2 = t.z + aldv[2]; e2 = e2 > 0.f ? e2 : 0.2f * e2;
        e3 = t.w + aldv[3]; e3 = e3 > 0.f ? e3 : 0.2f * e3;
      }
    } else {
      if (act) {
        e0 = als[s_e] + aldv[0]; e0 = e0 > 0.f ? e0 : 0.2f * e0;
      }
    }
    float m0 = e0, m1 = e1, m2 = e2, m3 = e3;
#pragma unroll
    for (int off = 32; off >= 1; off >>= 1) {
      m0 = fmaxf(m0, __shfl_xor(m0, off));
      if constexpr (HH == 4) {
        m1 = fmaxf(m1, __shfl_xor(m1, off));
        m2 = fmaxf(m2, __shfl_xor(m2, off));
        m3 = fmaxf(m3, __shfl_xor(m3, off));
      }
    }
    float p0 = act ? __expf(e0 - m0) : 0.f;
    float p1 = 0.f, p2 = 0.f, p3 = 0.f;
    if constexpr (HH == 4) {
      p1 = act ? __expf(e1 - m1) : 0.f;
      p2 = act ? __expf(e2 - m2) : 0.f;
      p3 = act ? __expf(e3 - m3) : 0.f;
    }
    float s0 = p0, s1 = p1, s2 = p2, s3 = p3;
#pragma unroll
    for (int off = 32; off >= 1; off >>= 1) {
      s0 += __shfl_xor(s0, off);
      if constexpr (HH == 4) {
        s1 += __shfl_xor(s1, off);
        s2 += __shfl_xor(s2, off);
        s3 += __shfl_xor(s3, off);
      }
    }
    float a0 = p0 / (s0 + 1e-16f);
    float a1 = 0.f, a2 = 0.f, a3 = 0.f;
    if constexpr (HH == 4) {
      a1 = p1 / (s1 + 1e-16f);
      a2 = p2 / (s2 + 1e-16f);
      a3 = p3 / (s3 + 1e-16f);
    }

    // ---- grouped gather: NEG edges in flight, depth-2 pipeline ----
    int j = grp;
    int sj = __shfl(s_e, j < 64 ? j : 0);
    uint4v u = *(const uint4v*)(hb + (size_t)sj * W + c0);
    for (int j0 = 0; j0 < deg; j0 += NEG) {
      uint4v ucur = u;
      int jcur = j;
      j += NEG;
      if (j0 + NEG < deg) {
        int sn = __shfl(s_e, j < 64 ? j : 0);
        u = *(const uint4v*)(hb + (size_t)sn * W + c0);
      }
      int jc = jcur < 64 ? jcur : 0;
      float w;
      if constexpr (HH == 4) {
        float wa = __shfl(a0, jc), wb = __shfl(a1, jc), wcx = __shfl(a2, jc), wd = __shfl(a3, jc);
        w = sel4(wa, wb, wcx, wd);
      } else {
        w = __shfl(a0, jc);
      }
      if (jcur >= deg) w = 0.f;
#pragma unroll
      for (int i = 0; i < 4; ++i) {
        acc[2 * i]     = fmaf(w, hlo(ucur[i]), acc[2 * i]);
        acc[2 * i + 1] = fmaf(w, hhi(ucur[i]), acc[2 * i + 1]);
      }
    }
  } else {
    // ---- slow path (deg > 64) ----
    float me[HH];
#pragma unroll
    for (int h = 0; h < HH; ++h) me[h] = -1e30f;
    for (int k = begin + lane; k < end; k += 64) {
      int s = csr_src[k];
      if constexpr (HH == 4) {
        float4 t = *(const float4*)(als + (size_t)s * 4);
        float e0 = t.x + aldv[0]; e0 = e0 > 0.f ? e0 : 0.2f * e0; me[0] = fmaxf(me[0], e0);
        float e1 = t.y + aldv[1]; e1 = e1 > 0.f ? e1 : 0.2f * e1; me[1] = fmaxf(me[1], e1);
        float e2 = t.z + aldv[2]; e2 = e2 > 0.f ? e2 : 0.2f * e2; me[2] = fmaxf(me[2], e2);
        float e3 = t.w + aldv[3]; e3 = e3 > 0.f ? e3 : 0.2f * e3; me[3] = fmaxf(me[3], e3);
      } else {
        float e0 = als[s] + aldv[0]; e0 = e0 > 0.f ? e0 : 0.2f * e0; me[0] = fmaxf(me[0], e0);
      }
    }
#pragma unroll
    for (int off = 32; off >= 1; off >>= 1)
#pragma unroll
      for (int h = 0; h < HH; ++h) me[h] = fmaxf(me[h], __shfl_xor(me[h], off));
    float se[HH];
#pragma unroll
    for (int h = 0; h < HH; ++h) se[h] = 0.f;
    for (int k = begin + lane; k < end; k += 64) {
      int s = csr_src[k];
      if constexpr (HH == 4) {
        float4 t = *(const float4*)(als + (size_t)s * 4);
        float e0 = t.x + aldv[0]; e0 = e0 > 0.f ? e0 : 0.2f * e0; se[0] += __expf(e0 - me[0]);
        float e1 = t.y + aldv[1]; e1 = e1 > 0.f ? e1 : 0.2f * e1; se[1] += __expf(e1 - me[1]);
        float e2 = t.z + aldv[2]; e2 = e2 > 0.f ? e2 : 0.2f * e2; se[2] += __expf(e2 - me[2]);
        float e3 = t.w + aldv[3]; e3 = e3 > 0.f ? e3 : 0.2f * e3; se[3] += __expf(e3 - me[3]);
      } else {
        float e0 = als[s] + aldv[0]; e0 = e0 > 0.f ? e0 : 0.2f * e0; se[0] += __expf(e0 - me[0]);
      }
    }
#pragma unroll
    for (int off = 32; off >= 1; off >>= 1)
#pragma unroll
      for (int h = 0; h < HH; ++h) se[h] += __shfl_xor(se[h], off);
    float inv[HH];
#pragma unroll
    for (int h = 0; h < HH; ++h) inv[h] = 1.f / (se[h] + 1e-16f);

    float m_my, i_my, ad_my;
    if constexpr (HH == 4) {
      m_my = sel4(me[0], me[1], me[2], me[3]);
      i_my = sel4(inv[0], inv[1], inv[2], inv[3]);
      ad_my = sel4(aldv[0], aldv[1], aldv[2], aldv[3]);
    } else {
      m_my = me[0]; i_my = inv[0]; ad_my = aldv[0];
    }
    for (int j0 = 0; j0 < deg; j0 += NEG) {
      int j = j0 + grp;
      if (j < deg) {
        int s = csr_src[begin + j];
        float as_my;
        if constexpr (HH == 4) {
          float4 t = *(const float4*)(als + (size_t)s * 4);
          as_my = sel4(t.x, t.y, t.z, t.w);
        } else {
          as_my = als[s];
        }
        float e = as_my + ad_my; e = e > 0.f ? e : 0.2f * e;
        float w = __expf(e - m_my) * i_my;
        uint4v u = *(const uint4v*)(hb + (size_t)s * W + c0);
#pragma unroll
        for (int i = 0; i < 4; ++i) {
          acc[2 * i]     = fmaf(w, hlo(u[i]), acc[2 * i]);
          acc[2 * i + 1] = fmaf(w, hhi(u[i]), acc[2 * i + 1]);
        }
      }
    }
  }
  }  // end non-fast16

  // ---- cross-group reduce: sum over edge groups ----
#pragma unroll
  for (int i = 0; i < 8; ++i) {
    if constexpr (HH == 1) acc[i] += __shfl_xor(acc[i], 8);
    acc[i] += __shfl_xor(acc[i], 16);
    acc[i] += __shfl_xor(acc[i], 32);
  }

  // ---- bias + LayerNorm + ELU on my 8 channels ----
  float4 bv0 = *(const float4*)(bias + c0);
  float4 bv1 = *(const float4*)(bias + c0 + 4);
  float v[8];
  v[0] = acc[0] + bv0.x; v[1] = acc[1] + bv0.y; v[2] = acc[2] + bv0.z; v[3] = acc[3] + bv0.w;
  v[4] = acc[4] + bv1.x; v[5] = acc[5] + bv1.y; v[6] = acc[6] + bv1.z; v[7] = acc[7] + bv1.w;
  float sm = 0.f, s2 = 0.f;
#pragma unroll
  for (int i = 0; i < 8; ++i) { sm += v[i]; s2 += v[i] * v[i]; }
  constexpr int TOPOFF = LPE / 2;  // 8 (W=128) or 4 (W=64)
#pragma unroll
  for (int off = TOPOFF; off >= 1; off >>= 1) {
    sm += __shfl_xor(sm, off);
    s2 += __shfl_xor(s2, off);
  }
  const float invW = 1.0f / W;
  float mu = sm * invW;
  float var = s2 * invW - mu * mu;
  float r = rsqrtf(var + 1e-5f);
  float4 gv0 = *(const float4*)(g + c0);
  float4 gv1 = *(const float4*)(g + c0 + 4);
  float4 be0 = *(const float4*)(be + c0);
  float4 be1 = *(const float4*)(be + c0 + 4);
  float gg[8] = {gv0.x, gv0.y, gv0.z, gv0.w, gv1.x, gv1.y, gv1.z, gv1.w};
  float bb[8] = {be0.x, be0.y, be0.z, be0.w, be1.x, be1.y, be1.z, be1.w};
  uint4v pk;
#pragma unroll
  for (int i = 0; i < 4; ++i) {
    float y0 = gg[2 * i] * (v[2 * i] - mu) * r + bb[2 * i];
    y0 = y0 > 0.f ? y0 : __expf(y0) - 1.f;
    float y1 = gg[2 * i + 1] * (v[2 * i + 1] - mu) * r + bb[2 * i + 1];
    y1 = y1 > 0.f ? y1 : __expf(y1) - 1.f;
    pk[i] = (uint)f2h(y0) | ((uint)f2h(y1) << 16);
  }
  if (grp == 0)
    *(uint4v*)(xout + (size_t)wid * W + c0) = pk;
}

// ---------- pooling over fp16 h3 (64 partial blocks) ----------
__global__ void pool_partial(const ushort* __restrict__ h, float* __restrict__ psum,
                             float* __restrict__ pmax, int n) {
  int tid = threadIdx.x;
  float lsum = 0.f, lmax = -1e30f;
  for (size_t idx = (size_t)blockIdx.x * 256 + tid; idx < (size_t)n * 64;
       idx += (size_t)gridDim.x * 256) {
    float v = h2f(h[idx]);
    lsum += v;
    lmax = fmaxf(lmax, v);
  }
  __shared__ float ss[256], sm[256];
  ss[tid] = lsum; sm[tid] = lmax;
  __syncthreads();
  if (tid < 64) {
    float a = ss[tid] + ss[tid + 64] + ss[tid + 128] + ss[tid + 192];
    float m = fmaxf(fmaxf(sm[tid], sm[tid + 64]), fmaxf(sm[tid + 128], sm[tid + 192]));
    psum[blockIdx.x * 64 + tid] = a;
    pmax[blockIdx.x * 64 + tid] = m;
  }
}

// ---------- parallel final reduce + classifier (256 threads, 1 block) ----------
__global__ __launch_bounds__(256) void pool_final(
    const float* __restrict__ psum, const float* __restrict__ pmax,
    int nblocks, int n, const float* __restrict__ cW1,
    const float* __restrict__ cb1, const float* __restrict__ cW2,
    const float* __restrict__ cb2, float* __restrict__ out) {
  __shared__ float sred[4][64], mred[4][64];
  __shared__ float z[128];
  __shared__ float hid[128];
  int tid = threadIdx.x;
  int c = tid & 63, q = tid >> 6;  // q in 0..3
  float s = 0.f, m = -1e30f;
  for (int b = q; b < nblocks; b += 4) {
    s += psum[b * 64 + c];
    m = fmaxf(m, pmax[b * 64 + c]);
  }
  sred[q][c] = s; mred[q][c] = m;
  __syncthreads();
  if (q == 0) {
    float st = sred[0][c] + sred[1][c] + sred[2][c] + sred[3][c];
    float mt = fmaxf(fmaxf(mred[0][c], mred[1][c]), fmaxf(mred[2][c], mred[3][c]));
    z[c] = st / (float)n;
    z[64 + c] = mt;
  }
  __syncthreads();
  if (tid < 128) {
    float a = cb1[tid];
#pragma unroll 4
    for (int k = 0; k < 128; ++k) a += z[k] * cW1[k * 128 + tid];
    hid[tid] = fmaxf(a, 0.f);
  }
  __syncthreads();
  if (tid < 2) {
    float o = cb2[tid];
    for (int j = 0; j < 128; ++j) o += hid[j] * cW2[j * 2 + tid];
    out[tid] = o;
  }
}

static inline int cdiv(long long a, long long b) { return (int)((a + b - 1) / b); }

extern "C" void kernel_launch(void* const* d_in, const int* in_sizes, int n_in,
                              void* d_out, int out_size, void* d_ws, size_t ws_size,
                              hipStream_t stream) {
  const float* x   = (const float*)d_in[0];
  const int*   ei  = (const int*)d_in[1];
  const float* W1  = (const float*)d_in[3];
  const float* as1 = (const float*)d_in[4];
  const float* ad1 = (const float*)d_in[5];
  const float* b1  = (const float*)d_in[6];
  const float* g1  = (const float*)d_in[7];
  const float* be1 = (const float*)d_in[8];
  const float* W2  = (const float*)d_in[9];
  const float* as2 = (const float*)d_in[10];
  const float* ad2 = (const float*)d_in[11];
  const float* b2  = (const float*)d_in[12];
  const float* g2  = (const float*)d_in[13];
  const float* be2 = (const float*)d_in[14];
  const float* W3  = (const float*)d_in[15];
  const float* as3 = (const float*)d_in[16];
  const float* ad3 = (const float*)d_in[17];
  const float* b3  = (const float*)d_in[18];
  const float* g3  = (const float*)d_in[19];
  const float* be3 = (const float*)d_in[20];
  const float* cW1 = (const float*)d_in[21];
  const float* cb1 = (const float*)d_in[22];
  const float* cW2 = (const float*)d_in[23];
  const float* cb2 = (const float*)d_in[24];
  float* out = (float*)d_out;

  const int N   = in_sizes[2];
  const int E0  = in_sizes[1] / 2;
  const int Et  = E0 + N;
  const int FIN = in_sizes[0] / N;

  float* ws = (float*)d_ws;
  size_t o = 0;
  ushort* Ab = (ushort*)(ws + o); o += (size_t)N * 64;   // N x 128 fp16 (h)
  ushort* Bb = (ushort*)(ws + o); o += (size_t)N * 64;   // N x 128 fp16 (x_l)
  float* als  = ws + o; o += (size_t)N * 4;
  float* ald  = ws + o; o += (size_t)N * 4;
  ushort* Wt1 = (ushort*)(ws + o); o += (128 * 512) / 2;
  ushort* Wt2 = (ushort*)(ws + o); o += (128 * 128) / 2;
  ushort* Wt3 = (ushort*)(ws + o); o += (64 * 128) / 2;
  float* psum = ws + o; o += 64 * 64;
  float* pmax = ws + o; o += 64 * 64;
  int* counts  = (int*)(ws + o); o += N + 1;
  int* offsets = (int*)(ws + o); o += N + 1;
  int* cursor  = (int*)(ws + o); o += N;
  int* bsum    = (int*)(ws + o); o += 256;
  int* csr_src = (int*)(ws + o); o += Et;

  const int* esrc = ei;
  const int* edst = ei + E0;
  const int NB = cdiv(N, 256);

  // ===== weight prep (single launch) =====
  prep_wt3<<<cdiv((long long)FIN * 128 + 128 * 128 + 128 * 64, TPB), TPB, 0, stream>>>(
      W1, Wt1, W2, Wt2, W3, Wt3, FIN);

  // ===== CSR build (once, reused by all 3 layers) =====
  zero_int<<<cdiv(N + 1, TPB), TPB, 0, stream>>>(counts, N + 1);
  hist_dst<<<cdiv(Et, TPB), TPB, 0, stream>>>(edst, counts, E0, Et);
  block_sums<<<NB, 256, 0, stream>>>(counts, bsum, N);
  scan_bsum<<<1, 256, 0, stream>>>(bsum, NB);
  scan_final<<<NB, 256, 0, stream>>>(counts, bsum, offsets, cursor, N, Et);
  scatter_csr<<<cdiv(Et, TPB), TPB, 0, stream>>>(esrc, edst, cursor, csr_src, E0, Et);

  // ===== Layer 1: x[N,512] fp32 -> h(Ab)+al -> x1(Bb) =====
  gemm_mfma<0, 128, 1><<<cdiv(N, 64), 256, 0, stream>>>(x, Wt1, Ab, N, FIN, as1, ad1, als, ald);
  fused_attn<4, 32><<<cdiv(N, 4), 256, 0, stream>>>(Ab, als, ald, offsets, csr_src, b1, g1, be1, Bb, N);
  // ===== Layer 2: x1(Bb) -> h(Ab)+al -> x2(Bb) =====
  gemm_mfma<1, 128, 1><<<cdiv(N, 64), 256, 0, stream>>>(Bb, Wt2, Ab, N, 128, as2, ad2, als, ald);
  fused_attn<4, 32><<<cdiv(N, 4), 256, 0, stream>>>(Ab, als, ald, offsets, csr_src, b2, g2, be2, Bb, N);
  // ===== Layer 3: x2(Bb) -> h[N,64](Ab)+al -> x3(Bb) =====
  gemm_mfma<1, 64, 2><<<cdiv(N, 64), 256, 0, stream>>>(Bb, Wt3, Ab, N, 128, as3, ad3, als, ald);
  fused_attn<1, 64><<<cdiv(N, 4), 256, 0, stream>>>(Ab, als, ald, offsets, csr_src, b3, g3, be3, Bb, N);
  // ===== Pool + classifier =====
  pool_partial<<<64, 256, 0, stream>>>(Bb, psum, pmax, N);
  pool_final<<<1, 256, 0, stream>>>(psum, pmax, 64, N, cW1, cb1, cW2, cb2, out);
}

// Round 16
// 319.919 us; speedup vs baseline: 1.0154x; 1.0154x over previous
//
#include <hip/hip_runtime.h>
#include <cmath>

static constexpr int TPB = 256;

using short8 = __attribute__((ext_vector_type(8))) short;
using half8  = __attribute__((ext_vector_type(8))) _Float16;
using f32x4  = __attribute__((ext_vector_type(4))) float;
using uint4v = __attribute__((ext_vector_type(4))) unsigned int;
typedef unsigned short ushort;
typedef unsigned int uint;

// fp16 helpers (RNE via hardware convert)
__device__ __forceinline__ ushort f2h(float f) {
  _Float16 h = (_Float16)f;
  return __builtin_bit_cast(ushort, h);
}
__device__ __forceinline__ float h2f(ushort u) {
  return (float)__builtin_bit_cast(_Float16, u);
}
__device__ __forceinline__ float hlo(uint u) { return h2f((ushort)(u & 0xffffu)); }
__device__ __forceinline__ float hhi(uint u) { return h2f((ushort)(u >> 16)); }

// ---------- all three W [K][Nc] fp32 -> Wt [Nc][K] fp16, one launch ----------
__global__ void prep_wt3(const float* __restrict__ W1, ushort* __restrict__ Wt1,
                         const float* __restrict__ W2, ushort* __restrict__ Wt2,
                         const float* __restrict__ W3, ushort* __restrict__ Wt3,
                         int FIN) {
  int idx = blockIdx.x * TPB + threadIdx.x;
  const int n1 = FIN * 128, n2 = 128 * 128, n3 = 128 * 64;
  if (idx < n1) {
    int nc = idx / FIN, k = idx - nc * FIN;
    Wt1[idx] = f2h(W1[(size_t)k * 128 + nc]);
  } else if (idx < n1 + n2) {
    int i = idx - n1;
    int nc = i / 128, k = i - nc * 128;
    Wt2[i] = f2h(W2[(size_t)k * 128 + nc]);
  } else if (idx < n1 + n2 + n3) {
    int i = idx - n1 - n2;
    int nc = i / 128, k = i - nc * 128;
    Wt3[i] = f2h(W3[(size_t)k * 64 + nc]);
  }
}

// ---------- MFMA GEMM (fp16): C[n,BN](fp16) = A[n,K] @ W[K,BN] ----------
// BM=64, BN=Nc (64 or 128), BK=64, 256 threads = 4 waves (2 row x 2 col)
// Single-buffered (r14 dbuf traded residency for pipeline — net neutral/worse).
// FUSEMODE: 0 = none; 1 = 4-head als/ald (BN=128, C=32); 2 = 1-head als/ald (BN=64)
template <int ABF16, int BN, int FUSEMODE>
__global__ __launch_bounds__(256) void gemm_mfma(const void* __restrict__ Ap,
                                                 const ushort* __restrict__ Wt,
                                                 ushort* __restrict__ Cb,
                                                 int n, int K,
                                                 const float* __restrict__ a_s,
                                                 const float* __restrict__ a_d,
                                                 float* __restrict__ als,
                                                 float* __restrict__ ald) {
  constexpr int NF = BN / 32;  // col frags per wave (4 or 2)
  __shared__ short As[64 * 72];
  __shared__ short Bs[BN * 72];
  const int tid = threadIdx.x;
  const int row0 = blockIdx.x * 64;
  const int srow = tid >> 2, sks = (tid & 3) << 4;  // A staging
  const int wave = tid >> 6, lane = tid & 63;
  const int wr = wave >> 1, wc = wave & 1;
  const int lm = lane & 15, lg = lane >> 4;

  f32x4 acc[2][NF] = {};

  for (int k0 = 0; k0 < K; k0 += 64) {
    {
      int gr = row0 + srow;
      short8 v0 = {0, 0, 0, 0, 0, 0, 0, 0}, v1 = v0;
      if constexpr (ABF16 == 0) {
        const float* A = (const float*)Ap;
        if (gr < n) {
          const float* p = A + (size_t)gr * K + k0 + sks;
          float4 f0 = *(const float4*)(p + 0);
          float4 f1 = *(const float4*)(p + 4);
          float4 f2 = *(const float4*)(p + 8);
          float4 f3 = *(const float4*)(p + 12);
          v0[0] = (short)f2h(f0.x); v0[1] = (short)f2h(f0.y); v0[2] = (short)f2h(f0.z); v0[3] = (short)f2h(f0.w);
          v0[4] = (short)f2h(f1.x); v0[5] = (short)f2h(f1.y); v0[6] = (short)f2h(f1.z); v0[7] = (short)f2h(f1.w);
          v1[0] = (short)f2h(f2.x); v1[1] = (short)f2h(f2.y); v1[2] = (short)f2h(f2.z); v1[3] = (short)f2h(f2.w);
          v1[4] = (short)f2h(f3.x); v1[5] = (short)f2h(f3.y); v1[6] = (short)f2h(f3.z); v1[7] = (short)f2h(f3.w);
        }
      } else {
        const ushort* A = (const ushort*)Ap;
        if (gr < n) {
          const ushort* p = A + (size_t)gr * K + k0 + sks;
          v0 = *(const short8*)(p + 0);
          v1 = *(const short8*)(p + 8);
        }
      }
      *(short8*)&As[srow * 72 + sks + 0] = v0;
      *(short8*)&As[srow * 72 + sks + 8] = v1;
    }
    if constexpr (BN == 128) {
      const int brow = tid >> 1, bks = (tid & 1) << 5;
      const ushort* wp = Wt + (size_t)brow * K + k0 + bks;
      *(short8*)&Bs[brow * 72 + bks + 0]  = *(const short8*)(wp + 0);
      *(short8*)&Bs[brow * 72 + bks + 8]  = *(const short8*)(wp + 8);
      *(short8*)&Bs[brow * 72 + bks + 16] = *(const short8*)(wp + 16);
      *(short8*)&Bs[brow * 72 + bks + 24] = *(const short8*)(wp + 24);
    } else {
      const ushort* wp = Wt + (size_t)srow * K + k0 + sks;
      *(short8*)&Bs[srow * 72 + sks + 0] = *(const short8*)(wp + 0);
      *(short8*)&Bs[srow * 72 + sks + 8] = *(const short8*)(wp + 8);
    }
    __syncthreads();
#pragma unroll
    for (int kk = 0; kk < 64; kk += 32) {
      half8 a0 = *(const half8*)&As[(wr * 32 + lm) * 72 + kk + lg * 8];
      half8 a1 = *(const half8*)&As[(wr * 32 + 16 + lm) * 72 + kk + lg * 8];
      half8 bf[NF];
#pragma unroll
      for (int f = 0; f < NF; ++f)
        bf[f] = *(const half8*)&Bs[(wc * (BN / 2) + f * 16 + lm) * 72 + kk + lg * 8];
#pragma unroll
      for (int f = 0; f < NF; ++f) {
        acc[0][f] = __builtin_amdgcn_mfma_f32_16x16x32_f16(a0, bf[f], acc[0][f], 0, 0, 0);
        acc[1][f] = __builtin_amdgcn_mfma_f32_16x16x32_f16(a1, bf[f], acc[1][f], 0, 0, 0);
      }
    }
    __syncthreads();
  }
#pragma unroll
  for (int m = 0; m < 2; ++m)
#pragma unroll
    for (int f = 0; f < NF; ++f)
#pragma unroll
      for (int r = 0; r < 4; ++r) {
        int row = row0 + wr * 32 + m * 16 + lg * 4 + r;
        if (row < n) {
          int col = wc * (BN / 2) + f * 16 + lm;
          Cb[(size_t)row * BN + col] = f2h(acc[m][f][r]);
        }
      }
  if constexpr (FUSEMODE == 1) {
    // 4-head logits: head = 2*wc + hh, 32 contiguous cols fully in-wave
#pragma unroll
    for (int hh = 0; hh < 2; ++hh) {
      const int head = 2 * wc + hh;
      float as0 = a_s[head * 32 + lm], as1 = a_s[head * 32 + 16 + lm];
      float ad0 = a_d[head * 32 + lm], ad1 = a_d[head * 32 + 16 + lm];
#pragma unroll
      for (int m = 0; m < 2; ++m)
#pragma unroll
        for (int r = 0; r < 4; ++r) {
          float tS = acc[m][2 * hh][r] * as0 + acc[m][2 * hh + 1][r] * as1;
          float tD = acc[m][2 * hh][r] * ad0 + acc[m][2 * hh + 1][r] * ad1;
#pragma unroll
          for (int off = 8; off >= 1; off >>= 1) {
            tS += __shfl_xor(tS, off);
            tD += __shfl_xor(tD, off);
          }
          if (lm == 0) {
            int row = row0 + wr * 32 + m * 16 + lg * 4 + r;
            if (row < n) {
              als[(size_t)row * 4 + head] = tS;
              ald[(size_t)row * 4 + head] = tD;
            }
          }
        }
    }
  }
  if constexpr (FUSEMODE == 2) {
    // 1-head logits over 64 cols split across wc=0 (cols 0-31) and wc=1 (32-63).
    // Cross-wave combine via LDS scratch (As is dead after the last barrier).
    float* alsp = (float*)As;        // 64 floats
    float* aldp = alsp + 64;
    float tS[2][4], tD[2][4];
#pragma unroll
    for (int m = 0; m < 2; ++m)
#pragma unroll
      for (int r = 0; r < 4; ++r) {
        int col0c = wc * 32;
        float s = acc[m][0][r] * a_s[col0c + lm] + acc[m][1][r] * a_s[col0c + 16 + lm];
        float dd = acc[m][0][r] * a_d[col0c + lm] + acc[m][1][r] * a_d[col0c + 16 + lm];
#pragma unroll
        for (int off = 8; off >= 1; off >>= 1) {
          s += __shfl_xor(s, off);
          dd += __shfl_xor(dd, off);
        }
        tS[m][r] = s;
        tD[m][r] = dd;
      }
    if (wc == 0) {
#pragma unroll
      for (int m = 0; m < 2; ++m)
#pragma unroll
        for (int r = 0; r < 4; ++r)
          if (lm == 0) {
            int rl = wr * 32 + m * 16 + lg * 4 + r;
            alsp[rl] = tS[m][r];
            aldp[rl] = tD[m][r];
          }
    }
    __syncthreads();
    if (wc == 1) {
#pragma unroll
      for (int m = 0; m < 2; ++m)
#pragma unroll
        for (int r = 0; r < 4; ++r)
          if (lm == 0) {
            int rl = wr * 32 + m * 16 + lg * 4 + r;
            int row = row0 + rl;
            if (row < n) {
              als[row] = alsp[rl] + tS[m][r];
              ald[row] = aldp[rl] + tD[m][r];
            }
          }
    }
  }
}

// ---------- CSR build ----------
__global__ void zero_int(int* __restrict__ p, int n) {
  int i = blockIdx.x * TPB + threadIdx.x;
  if (i < n) p[i] = 0;
}

__global__ void hist_dst(const int* __restrict__ edst, int* __restrict__ counts,
                         int E0, int Et) {
  int e = blockIdx.x * TPB + threadIdx.x;
  if (e >= Et) return;
  int d = e < E0 ? edst[e] : e - E0;
  atomicAdd(&counts[d], 1);
}

__global__ void block_sums(const int* __restrict__ counts, int* __restrict__ bsum, int N) {
  __shared__ int sh[256];
  int t = threadIdx.x, idx = blockIdx.x * 256 + t;
  sh[t] = idx < N ? counts[idx] : 0;
  __syncthreads();
  for (int off = 128; off >= 1; off >>= 1) {
    if (t < off) sh[t] += sh[t + off];
    __syncthreads();
  }
  if (t == 0) bsum[blockIdx.x] = sh[0];
}

__global__ void scan_bsum(int* __restrict__ bsum, int nb) {
  __shared__ int sh[256];
  int t = threadIdx.x;
  int v = t < nb ? bsum[t] : 0;
  sh[t] = v;
  __syncthreads();
  for (int off = 1; off < 256; off <<= 1) {
    int u = (t >= off) ? sh[t - off] : 0;
    __syncthreads();
    sh[t] += u;
    __syncthreads();
  }
  if (t < nb) bsum[t] = sh[t] - v;  // exclusive
}

__global__ void scan_final(const int* __restrict__ counts, const int* __restrict__ bsum_ex,
                           int* __restrict__ offsets, int* __restrict__ cursor,
                           int N, int Et) {
  __shared__ int sh[256];
  int t = threadIdx.x, b = blockIdx.x;
  int idx = b * 256 + t;
  int v = (idx < N) ? counts[idx] : 0;
  sh[t] = v;
  __syncthreads();
  for (int off = 1; off < 256; off <<= 1) {
    int u = (t >= off) ? sh[t - off] : 0;
    __syncthreads();
    sh[t] += u;
    __syncthreads();
  }
  if (idx < N) {
    int o = bsum_ex[b] + sh[t] - v;
    offsets[idx] = o;
    cursor[idx] = o;
  }
  if (idx == 0) offsets[N] = Et;
}

__global__ void scatter_csr(const int* __restrict__ esrc, const int* __restrict__ edst,
                            int* __restrict__ cursor, int* __restrict__ csr_src,
                            int E0, int Et) {
  int e = blockIdx.x * TPB + threadIdx.x;
  if (e >= Et) return;
  int s = e < E0 ? esrc[e] : e - E0;
  int d = e < E0 ? edst[e] : e - E0;
  int pos = atomicAdd(&cursor[d], 1);
  csr_src[pos] = s;
}

// ---------- fused attention + bias + LayerNorm + ELU, one wave per dst node ----------
template <int HH, int CC>
__global__ __launch_bounds__(256) void fused_attn(
    const ushort* __restrict__ hb, const float* __restrict__ als,
    const float* __restrict__ ald, const int* __restrict__ offsets,
    const int* __restrict__ csr_src, const float* __restrict__ bias,
    const float* __restrict__ g, const float* __restrict__ be,
    ushort* __restrict__ xout, int n) {
  constexpr int W = HH * CC;        // 128 or 64
  constexpr int LPE = W / 8;        // 16 or 8 lanes per edge
  constexpr int NEG = 64 / LPE;     // 4 or 8 concurrent edges
  int wid = (int)((blockIdx.x * (size_t)blockDim.x + threadIdx.x) >> 6);
  int lane = threadIdx.x & 63;
  if (wid >= n) return;
  const int d = wid;
  const int begin = offsets[d], end = offsets[d + 1];
  const int deg = end - begin;

  const int grp = lane / LPE, sub = lane % LPE;
  const int c0 = sub * 8;

  float acc[8] = {};

  if (HH == 4 && deg <= 16) {
    // ======== FAST16 path: lane = (head h16, edge j16) ========
    const int h16 = lane >> 4, j16 = lane & 15;
    bool act = j16 < deg;
    int s_e = csr_src[begin + (act ? j16 : 0)];
    float e;
    {
      float ad_h = ald[(size_t)d * 4 + h16];
      e = act ? (als[(size_t)s_e * 4 + h16] + ad_h) : -1e30f;
      e = e > 0.f ? e : 0.2f * e;
    }
    float m = e;
#pragma unroll
    for (int off = 8; off >= 1; off >>= 1) m = fmaxf(m, __shfl_xor(m, off));
    float p = act ? __expf(e - m) : 0.f;
    float s = p;
#pragma unroll
    for (int off = 8; off >= 1; off >>= 1) s += __shfl_xor(s, off);
    float alpha = p / (s + 1e-16f);  // 0 for inactive lanes

    const int hc = sub >> 2;          // head of my channel block
    int j = grp;
    int sj = __shfl(s_e, j & 15);
    uint4v u = *(const uint4v*)(hb + (size_t)sj * W + c0);
    for (int j0 = 0; j0 < deg; j0 += NEG) {
      uint4v ucur = u;
      int jcur = j;
      j += NEG;
      if (j0 + NEG < deg) {
        int sn = __shfl(s_e, j & 15);
        u = *(const uint4v*)(hb + (size_t)sn * W + c0);
      }
      float w = __shfl(alpha, (hc << 4) | (jcur & 15));  // 0 if jcur >= deg
#pragma unroll
      for (int i = 0; i < 4; ++i) {
        acc[2 * i]     = fmaf(w, hlo(ucur[i]), acc[2 * i]);
        acc[2 * i + 1] = fmaf(w, hhi(ucur[i]), acc[2 * i + 1]);
      }
    }
  } else {

  const int hsel = sub >> 2;        // my head (HH=4)
  float aldv[HH];
  if constexpr (HH == 4) {
    float4 t = *(const float4*)(ald + (size_t)d * 4);
    aldv[0] = t.x; aldv[1] = t.y; aldv[2] = t.z; aldv[3] = t.w;
  } else {
    aldv[0] = ald[d];
  }

  auto sel4 = [&](float x0, float x1, float x2, float x3) {
    float lo = (hsel & 1) ? x1 : x0;
    float hi = (hsel & 1) ? x3 : x2;
    return (hsel & 2) ? hi : lo;
  };

  if (deg <= 64) {
    // ---- logits: one lane per edge ----
    bool act = lane < deg;
    int s_e = act ? csr_src[begin + lane] : 0;
    float e0 = -1e30f, e1 = -1e30f, e2 = -1e30f, e3 = -1e30f;
    if constexpr (HH == 4) {
      if (act) {
        float4 t = *(const float4*)(als + (size_t)s_e * 4);
        e0 = t.x + aldv[0]; e0 = e0 > 0.f ? e0 : 0.2f * e0;
        e1 = t.y + aldv[1]; e1 = e1 > 0.f ? e1 : 0.2f * e1;
        e2 = t.z + aldv[2]; e2 = e2 > 0.f ? e2 : 0.2f * e2;
        e3 = t.w + aldv[3]; e3 = e3 > 0.f ? e3 : 0.2f * e3;
      }
    } else {
      if (act) {
        e0 = als[s_e] + aldv[0]; e0 = e0 > 0.f ? e0 : 0.2f * e0;
      }
    }
    float m0 = e0, m1 = e1, m2 = e2, m3 = e3;
#pragma unroll
    for (int off = 32; off >= 1; off >>= 1) {
      m0 = fmaxf(m0, __shfl_xor(m0, off));
      if constexpr (HH == 4) {
        m1 = fmaxf(m1, __shfl_xor(m1, off));
        m2 = fmaxf(m2, __shfl_xor(m2, off));
        m3 = fmaxf(m3, __shfl_xor(m3, off));
      }
    }
    float p0 = act ? __expf(e0 - m0) : 0.f;
    float p1 = 0.f, p2 = 0.f, p3 = 0.f;
    if constexpr (HH == 4) {
      p1 = act ? __expf(e1 - m1) : 0.f;
      p2 = act ? __expf(e2 - m2) : 0.f;
      p3 = act ? __expf(e3 - m3) : 0.f;
    }
    float s0 = p0, s1 = p1, s2 = p2, s3 = p3;
#pragma unroll
    for (int off = 32; off >= 1; off >>= 1) {
      s0 += __shfl_xor(s0, off);
      if constexpr (HH == 4) {
        s1 += __shfl_xor(s1, off);
        s2 += __shfl_xor(s2, off);
        s3 += __shfl_xor(s3, off);
      }
    }
    float a0 = p0 / (s0 + 1e-16f);
    float a1 = 0.f, a2 = 0.f, a3 = 0.f;
    if constexpr (HH == 4) {
      a1 = p1 / (s1 + 1e-16f);
      a2 = p2 / (s2 + 1e-16f);
      a3 = p3 / (s3 + 1e-16f);
    }

    // ---- grouped gather: NEG edges in flight, depth-2 pipeline ----
    int j = grp;
    int sj = __shfl(s_e, j < 64 ? j : 0);
    uint4v u = *(const uint4v*)(hb + (size_t)sj * W + c0);
    for (int j0 = 0; j0 < deg; j0 += NEG) {
      uint4v ucur = u;
      int jcur = j;
      j += NEG;
      if (j0 + NEG < deg) {
        int sn = __shfl(s_e, j < 64 ? j : 0);
        u = *(const uint4v*)(hb + (size_t)sn * W + c0);
      }
      int jc = jcur < 64 ? jcur : 0;
      float w;
      if constexpr (HH == 4) {
        float wa = __shfl(a0, jc), wb = __shfl(a1, jc), wcx = __shfl(a2, jc), wd = __shfl(a3, jc);
        w = sel4(wa, wb, wcx, wd);
      } else {
        w = __shfl(a0, jc);
      }
      if (jcur >= deg) w = 0.f;
#pragma unroll
      for (int i = 0; i < 4; ++i) {
        acc[2 * i]     = fmaf(w, hlo(ucur[i]), acc[2 * i]);
        acc[2 * i + 1] = fmaf(w, hhi(ucur[i]), acc[2 * i + 1]);
      }
    }
  } else {
    // ---- slow path (deg > 64) ----
    float me[HH];
#pragma unroll
    for (int h = 0; h < HH; ++h) me[h] = -1e30f;
    for (int k = begin + lane; k < end; k += 64) {
      int s = csr_src[k];
      if constexpr (HH == 4) {
        float4 t = *(const float4*)(als + (size_t)s * 4);
        float e0 = t.x + aldv[0]; e0 = e0 > 0.f ? e0 : 0.2f * e0; me[0] = fmaxf(me[0], e0);
        float e1 = t.y + aldv[1]; e1 = e1 > 0.f ? e1 : 0.2f * e1; me[1] = fmaxf(me[1], e1);
        float e2 = t.z + aldv[2]; e2 = e2 > 0.f ? e2 : 0.2f * e2; me[2] = fmaxf(me[2], e2);
        float e3 = t.w + aldv[3]; e3 = e3 > 0.f ? e3 : 0.2f * e3; me[3] = fmaxf(me[3], e3);
      } else {
        float e0 = als[s] + aldv[0]; e0 = e0 > 0.f ? e0 : 0.2f * e0; me[0] = fmaxf(me[0], e0);
      }
    }
#pragma unroll
    for (int off = 32; off >= 1; off >>= 1)
#pragma unroll
      for (int h = 0; h < HH; ++h) me[h] = fmaxf(me[h], __shfl_xor(me[h], off));
    float se[HH];
#pragma unroll
    for (int h = 0; h < HH; ++h) se[h] = 0.f;
    for (int k = begin + lane; k < end; k += 64) {
      int s = csr_src[k];
      if constexpr (HH == 4) {
        float4 t = *(const float4*)(als + (size_t)s * 4);
        float e0 = t.x + aldv[0]; e0 = e0 > 0.f ? e0 : 0.2f * e0; se[0] += __expf(e0 - me[0]);
        float e1 = t.y + aldv[1]; e1 = e1 > 0.f ? e1 : 0.2f * e1; se[1] += __expf(e1 - me[1]);
        float e2 = t.z + aldv[2]; e2 = e2 > 0.f ? e2 : 0.2f * e2; se[2] += __expf(e2 - me[2]);
        float e3 = t.w + aldv[3]; e3 = e3 > 0.f ? e3 : 0.2f * e3; se[3] += __expf(e3 - me[3]);
      } else {
        float e0 = als[s] + aldv[0]; e0 = e0 > 0.f ? e0 : 0.2f * e0; se[0] += __expf(e0 - me[0]);
      }
    }
#pragma unroll
    for (int off = 32; off >= 1; off >>= 1)
#pragma unroll
      for (int h = 0; h < HH; ++h) se[h] += __shfl_xor(se[h], off);
    float inv[HH];
#pragma unroll
    for (int h = 0; h < HH; ++h) inv[h] = 1.f / (se[h] + 1e-16f);

    float m_my, i_my, ad_my;
    if constexpr (HH == 4) {
      m_my = sel4(me[0], me[1], me[2], me[3]);
      i_my = sel4(inv[0], inv[1], inv[2], inv[3]);
      ad_my = sel4(aldv[0], aldv[1], aldv[2], aldv[3]);
    } else {
      m_my = me[0]; i_my = inv[0]; ad_my = aldv[0];
    }
    for (int j0 = 0; j0 < deg; j0 += NEG) {
      int j = j0 + grp;
      if (j < deg) {
        int s = csr_src[begin + j];
        float as_my;
        if constexpr (HH == 4) {
          float4 t = *(const float4*)(als + (size_t)s * 4);
          as_my = sel4(t.x, t.y, t.z, t.w);
        } else {
          as_my = als[s];
        }
        float e = as_my + ad_my; e = e > 0.f ? e : 0.2f * e;
        float w = __expf(e - m_my) * i_my;
        uint4v u = *(const uint4v*)(hb + (size_t)s * W + c0);
#pragma unroll
        for (int i = 0; i < 4; ++i) {
          acc[2 * i]     = fmaf(w, hlo(u[i]), acc[2 * i]);
          acc[2 * i + 1] = fmaf(w, hhi(u[i]), acc[2 * i + 1]);
        }
      }
    }
  }
  }  // end non-fast16

  // ---- cross-group reduce: sum over edge groups ----
#pragma unroll
  for (int i = 0; i < 8; ++i) {
    if constexpr (HH == 1) acc[i] += __shfl_xor(acc[i], 8);
    acc[i] += __shfl_xor(acc[i], 16);
    acc[i] += __shfl_xor(acc[i], 32);
  }

  // ---- bias + LayerNorm + ELU on my 8 channels ----
  float4 bv0 = *(const float4*)(bias + c0);
  float4 bv1 = *(const float4*)(bias + c0 + 4);
  float v[8];
  v[0] = acc[0] + bv0.x; v[1] = acc[1] + bv0.y; v[2] = acc[2] + bv0.z; v[3] = acc[3] + bv0.w;
  v[4] = acc[4] + bv1.x; v[5] = acc[5] + bv1.y; v[6] = acc[6] + bv1.z; v[7] = acc[7] + bv1.w;
  float sm = 0.f, s2 = 0.f;
#pragma unroll
  for (int i = 0; i < 8; ++i) { sm += v[i]; s2 += v[i] * v[i]; }
  constexpr int TOPOFF = LPE / 2;  // 8 (W=128) or 4 (W=64)
#pragma unroll
  for (int off = TOPOFF; off >= 1; off >>= 1) {
    sm += __shfl_xor(sm, off);
    s2 += __shfl_xor(s2, off);
  }
  const float invW = 1.0f / W;
  float mu = sm * invW;
  float var = s2 * invW - mu * mu;
  float r = rsqrtf(var + 1e-5f);
  float4 gv0 = *(const float4*)(g + c0);
  float4 gv1 = *(const float4*)(g + c0 + 4);
  float4 be0 = *(const float4*)(be + c0);
  float4 be1 = *(const float4*)(be + c0 + 4);
  float gg[8] = {gv0.x, gv0.y, gv0.z, gv0.w, gv1.x, gv1.y, gv1.z, gv1.w};
  float bb[8] = {be0.x, be0.y, be0.z, be0.w, be1.x, be1.y, be1.z, be1.w};
  uint4v pk;
#pragma unroll
  for (int i = 0; i < 4; ++i) {
    float y0 = gg[2 * i] * (v[2 * i] - mu) * r + bb[2 * i];
    y0 = y0 > 0.f ? y0 : __expf(y0) - 1.f;
    float y1 = gg[2 * i + 1] * (v[2 * i + 1] - mu) * r + bb[2 * i + 1];
    y1 = y1 > 0.f ? y1 : __expf(y1) - 1.f;
    pk[i] = (uint)f2h(y0) | ((uint)f2h(y1) << 16);
  }
  if (grp == 0)
    *(uint4v*)(xout + (size_t)wid * W + c0) = pk;
}

// ---------- pooling over fp16 h3 (64 partial blocks) ----------
__global__ void pool_partial(const ushort* __restrict__ h, float* __restrict__ psum,
                             float* __restrict__ pmax, int n) {
  int tid = threadIdx.x;
  float lsum = 0.f, lmax = -1e30f;
  for (size_t idx = (size_t)blockIdx.x * 256 + tid; idx < (size_t)n * 64;
       idx += (size_t)gridDim.x * 256) {
    float v = h2f(h[idx]);
    lsum += v;
    lmax = fmaxf(lmax, v);
  }
  __shared__ float ss[256], sm[256];
  ss[tid] = lsum; sm[tid] = lmax;
  __syncthreads();
  if (tid < 64) {
    float a = ss[tid] + ss[tid + 64] + ss[tid + 128] + ss[tid + 192];
    float m = fmaxf(fmaxf(sm[tid], sm[tid + 64]), fmaxf(sm[tid + 128], sm[tid + 192]));
    psum[blockIdx.x * 64 + tid] = a;
    pmax[blockIdx.x * 64 + tid] = m;
  }
}

// ---------- parallel final reduce + classifier (256 threads, 1 block) ----------
__global__ __launch_bounds__(256) void pool_final(
    const float* __restrict__ psum, const float* __restrict__ pmax,
    int nblocks, int n, const float* __restrict__ cW1,
    const float* __restrict__ cb1, const float* __restrict__ cW2,
    const float* __restrict__ cb2, float* __restrict__ out) {
  __shared__ float sred[4][64], mred[4][64];
  __shared__ float z[128];
  __shared__ float hid[128];
  int tid = threadIdx.x;
  int c = tid & 63, q = tid >> 6;  // q in 0..3
  float s = 0.f, m = -1e30f;
  for (int b = q; b < nblocks; b += 4) {
    s += psum[b * 64 + c];
    m = fmaxf(m, pmax[b * 64 + c]);
  }
  sred[q][c] = s; mred[q][c] = m;
  __syncthreads();
  if (q == 0) {
    float st = sred[0][c] + sred[1][c] + sred[2][c] + sred[3][c];
    float mt = fmaxf(fmaxf(mred[0][c], mred[1][c]), fmaxf(mred[2][c], mred[3][c]));
    z[c] = st / (float)n;
    z[64 + c] = mt;
  }
  __syncthreads();
  if (tid < 128) {
    float a = cb1[tid];
#pragma unroll 4
    for (int k = 0; k < 128; ++k) a += z[k] * cW1[k * 128 + tid];
    hid[tid] = fmaxf(a, 0.f);
  }
  __syncthreads();
  if (tid < 2) {
    float o = cb2[tid];
    for (int j = 0; j < 128; ++j) o += hid[j] * cW2[j * 2 + tid];
    out[tid] = o;
  }
}

static inline int cdiv(long long a, long long b) { return (int)((a + b - 1) / b); }

extern "C" void kernel_launch(void* const* d_in, const int* in_sizes, int n_in,
                              void* d_out, int out_size, void* d_ws, size_t ws_size,
                              hipStream_t stream) {
  const float* x   = (const float*)d_in[0];
  const int*   ei  = (const int*)d_in[1];
  const float* W1  = (const float*)d_in[3];
  const float* as1 = (const float*)d_in[4];
  const float* ad1 = (const float*)d_in[5];
  const float* b1  = (const float*)d_in[6];
  const float* g1  = (const float*)d_in[7];
  const float* be1 = (const float*)d_in[8];
  const float* W2  = (const float*)d_in[9];
  const float* as2 = (const float*)d_in[10];
  const float* ad2 = (const float*)d_in[11];
  const float* b2  = (const float*)d_in[12];
  const float* g2  = (const float*)d_in[13];
  const float* be2 = (const float*)d_in[14];
  const float* W3  = (const float*)d_in[15];
  const float* as3 = (const float*)d_in[16];
  const float* ad3 = (const float*)d_in[17];
  const float* b3  = (const float*)d_in[18];
  const float* g3  = (const float*)d_in[19];
  const float* be3 = (const float*)d_in[20];
  const float* cW1 = (const float*)d_in[21];
  const float* cb1 = (const float*)d_in[22];
  const float* cW2 = (const float*)d_in[23];
  const float* cb2 = (const float*)d_in[24];
  float* out = (float*)d_out;

  const int N   = in_sizes[2];
  const int E0  = in_sizes[1] / 2;
  const int Et  = E0 + N;
  const int FIN = in_sizes[0] / N;

  float* ws = (float*)d_ws;
  size_t o = 0;
  ushort* Ab = (ushort*)(ws + o); o += (size_t)N * 64;   // N x 128 fp16 (h)
  ushort* Bb = (ushort*)(ws + o); o += (size_t)N * 64;   // N x 128 fp16 (x_l)
  float* als  = ws + o; o += (size_t)N * 4;
  float* ald  = ws + o; o += (size_t)N * 4;
  ushort* Wt1 = (ushort*)(ws + o); o += (128 * 512) / 2;
  ushort* Wt2 = (ushort*)(ws + o); o += (128 * 128) / 2;
  ushort* Wt3 = (ushort*)(ws + o); o += (64 * 128) / 2;
  float* psum = ws + o; o += 64 * 64;
  float* pmax = ws + o; o += 64 * 64;
  int* counts  = (int*)(ws + o); o += N + 1;
  int* offsets = (int*)(ws + o); o += N + 1;
  int* cursor  = (int*)(ws + o); o += N;
  int* bsum    = (int*)(ws + o); o += 256;
  int* csr_src = (int*)(ws + o); o += Et;

  const int* esrc = ei;
  const int* edst = ei + E0;
  const int NB = cdiv(N, 256);

  // ===== weight prep (single launch) =====
  prep_wt3<<<cdiv((long long)FIN * 128 + 128 * 128 + 128 * 64, TPB), TPB, 0, stream>>>(
      W1, Wt1, W2, Wt2, W3, Wt3, FIN);

  // ===== CSR build (once, reused by all 3 layers) =====
  zero_int<<<cdiv(N + 1, TPB), TPB, 0, stream>>>(counts, N + 1);
  hist_dst<<<cdiv(Et, TPB), TPB, 0, stream>>>(edst, counts, E0, Et);
  block_sums<<<NB, 256, 0, stream>>>(counts, bsum, N);
  scan_bsum<<<1, 256, 0, stream>>>(bsum, NB);
  scan_final<<<NB, 256, 0, stream>>>(counts, bsum, offsets, cursor, N, Et);
  scatter_csr<<<cdiv(Et, TPB), TPB, 0, stream>>>(esrc, edst, cursor, csr_src, E0, Et);

  // ===== Layer 1: x[N,512] fp32 -> h(Ab)+al -> x1(Bb) =====
  gemm_mfma<0, 128, 1><<<cdiv(N, 64), 256, 0, stream>>>(x, Wt1, Ab, N, FIN, as1, ad1, als, ald);
  fused_attn<4, 32><<<cdiv(N, 4), 256, 0, stream>>>(Ab, als, ald, offsets, csr_src, b1, g1, be1, Bb, N);
  // ===== Layer 2: x1(Bb) -> h(Ab)+al -> x2(Bb) =====
  gemm_mfma<1, 128, 1><<<cdiv(N, 64), 256, 0, stream>>>(Bb, Wt2, Ab, N, 128, as2, ad2, als, ald);
  fused_attn<4, 32><<<cdiv(N, 4), 256, 0, stream>>>(Ab, als, ald, offsets, csr_src, b2, g2, be2, Bb, N);
  // ===== Layer 3: x2(Bb) -> h[N,64](Ab)+al -> x3(Bb) =====
  gemm_mfma<1, 64, 2><<<cdiv(N, 64), 256, 0, stream>>>(Bb, Wt3, Ab, N, 128, as3, ad3, als, ald);
  fused_attn<1, 64><<<cdiv(N, 4), 256, 0, stream>>>(Ab, als, ald, offsets, csr_src, b3, g3, be3, Bb, N);
  // ===== Pool + classifier =====
  pool_partial<<<64, 256, 0, stream>>>(Bb, psum, pmax, N);
  pool_final<<<1, 256, 0, stream>>>(psum, pmax, 64, N, cW1, cb1, cW2, cb2, out);
}